// Round 14
// baseline (94.333 us; speedup 1.0000x reference)
//
#include <hip/hip_runtime.h>
#include <stdint.h>

#define NROWS 32768
#define DIMS  256
#define KCB   1024
#define MARGIN 0.25f

typedef _Float16 half8   __attribute__((ext_vector_type(8)));
typedef float    f32x4   __attribute__((ext_vector_type(4)));
typedef short    short4v __attribute__((ext_vector_type(4)));
typedef short    short8v __attribute__((ext_vector_type(8)));

// async global->LDS, 16B per lane; LDS dest = wave-uniform base + lane*16
__device__ __forceinline__ void gload_lds16(const void* g, void* l) {
    __builtin_amdgcn_global_load_lds(
        (const __attribute__((address_space(1))) uint32_t*)g,
        (__attribute__((address_space(3))) uint32_t*)l, 16, 0, 0);
}

__device__ __forceinline__ short f16h(float v) {
    _Float16 hh = (_Float16)v;
    return __builtin_bit_cast(short, hh);
}

// ---- E -> fragment-ordered f16 (h-plane) + he2 (verified rounds 9-13) ----
// code-group G (16 codes) = 8KB blob; chunk c (32 k) = 1KB at G*8192+c*1024 B;
// lane l holds code G*16+(l&15), k = c*32+(l>>4)*8..+7 at byte l*16.
__global__ __launch_bounds__(256) void esplit(const float* __restrict__ embed,
                                              short* __restrict__ Eh,
                                              float* __restrict__ he2) {
    int r = blockIdx.x * 4 + (threadIdx.x >> 6);   // code row 0..1023
    int l = threadIdx.x & 63;
    f32x4 v = ((const f32x4*)(embed + (size_t)r * DIMS))[l];
    float s = v[0]*v[0] + v[1]*v[1] + v[2]*v[2] + v[3]*v[3];
    #pragma unroll
    for (int off = 32; off > 0; off >>= 1) s += __shfl_down(s, off, 64);
    if (l == 0) he2[r] = 0.5f * s;
    int G = r >> 4, cc = l >> 3;
    int fl = (r & 15) + 16 * ((l >> 1) & 3);
    size_t base = (size_t)G * 4096 + cc * 512 + fl * 8 + (l & 1) * 4;
    short4v h;
    #pragma unroll
    for (int e = 0; e < 4; ++e) h[e] = f16h(v[e]);
    *(short4v*)(Eh + base) = h;
}

// ---- 16-lane-group exact dot (verified rounds 11-13) ---------------------
__device__ __forceinline__ float dot16(f32x4 xa, f32x4 xb, f32x4 xc, f32x4 xd,
                                       const float* __restrict__ erow, int q) {
    const f32x4* er = (const f32x4*)(erow + q * 16);
    f32x4 ea = er[0], eb = er[1], ec = er[2], ed = er[3];
    float s = xa[0] * ea[0];
    s = fmaf(xa[1], ea[1], s); s = fmaf(xa[2], ea[2], s); s = fmaf(xa[3], ea[3], s);
    s = fmaf(xb[0], eb[0], s); s = fmaf(xb[1], eb[1], s);
    s = fmaf(xb[2], eb[2], s); s = fmaf(xb[3], eb[3], s);
    s = fmaf(xc[0], ec[0], s); s = fmaf(xc[1], ec[1], s);
    s = fmaf(xc[2], ec[2], s); s = fmaf(xc[3], ec[3], s);
    s = fmaf(xd[0], ed[0], s); s = fmaf(xd[1], ed[1], s);
    s = fmaf(xd[2], ed[2], s); s = fmaf(xd[3], ed[3], s);
    s += __shfl_xor(s, 1, 64);
    s += __shfl_xor(s, 2, 64);
    s += __shfl_xor(s, 4, 64);
    s += __shfl_xor(s, 8, 64);
    return s;
}

// ==== fused: A-resident GEMM + argmax + combine + gather + rescue =========
// 256 blocks (1/CU) x 512 threads (8 waves). Wave w owns 16 rows (1 m-frag).
// LDS: A 64KB (wave-private 8KB: full-K f16 frags) | B dbuf 16KB (shared,
// counted-vmcnt depth-2) | per-group partials 12KB | he2 4KB.
__global__ __launch_bounds__(512, 2) void vq_fused(
    const float* __restrict__ x, const float* __restrict__ embed,
    const short* __restrict__ Eh, const float* __restrict__ he2,
    float* __restrict__ outq, float* __restrict__ outi)
{
    __shared__ char lds[98304];
    __shared__ int  idxS[128];
    __shared__ int  flagL[128];
    __shared__ int  flagN;

    char*  ldsA = lds;                       // 8 waves x 8KB
    char*  ldsB = lds + 65536;               // 2 x 8KB double buffer
    float* psB1 = (float*)(lds + 81920);     // [128][8]
    int*   psI1 = (int*)  (lds + 86016);
    float* psB2 = (float*)(lds + 90112);
    float* he2S = (float*)(lds + 94208);     // [1024]

    const int t = threadIdx.x, lane = t & 63, w = t >> 6;
    const int c15 = lane & 15, lhi = lane >> 4;
    const int rowBase = blockIdx.x * 128;
    const char* EhB = (const char*)Eh;

    if (t == 0) flagN = 0;

    // ---- prologue: A stage (convert x -> f16 frags, wave-private) --------
    {
        const int row = rowBase + w * 16 + c15;
        const float* xr = x + (size_t)row * DIMS + lhi * 8;
        #pragma unroll
        for (int c = 0; c < 8; ++c) {
            f32x4 a = *(const f32x4*)(xr + c * 32);
            f32x4 b = *(const f32x4*)(xr + c * 32 + 4);
            short8v h;
            #pragma unroll
            for (int e = 0; e < 4; ++e) { h[e] = f16h(a[e]); h[4 + e] = f16h(b[e]); }
            *(short8v*)(ldsA + w * 8192 + c * 1024 + lane * 16) = h;
        }
    }
    if (t < 256) {                           // he2 -> LDS
        f32x4 v = *(const f32x4*)(he2 + t * 4);
        *(f32x4*)(he2S + t * 4) = v;
    }
    __syncthreads();                         // drains vm+lgkm; outstanding=0

    // ---- B prologue: chunks 0,1 (1 gload per wave per chunk) -------------
    gload_lds16(EhB + (size_t)w * 8192 +        lane * 16, ldsB        + w * 1024);
    gload_lds16(EhB + (size_t)w * 8192 + 1024 + lane * 16, ldsB + 8192 + w * 1024);

    f32x4 acc[8];

#define CHUNK(CCV, WAITSTR, DOISS)                                            \
    {                                                                         \
        const int cc_ = (CCV);                                                \
        asm volatile(WAITSTR ::: "memory");                                   \
        __builtin_amdgcn_sched_barrier(0);                                    \
        __builtin_amdgcn_s_barrier();      /* chunk cc resident (all frags) */\
        const char* Bb = ldsB + (cc_ & 1) * 8192;                             \
        half8 Af = *(const half8*)(ldsA + w * 8192 + (cc_ & 7) * 1024 + lane * 16); \
        half8 Bf[8];                                                          \
        _Pragma("unroll")                                                     \
        for (int n = 0; n < 8; ++n)                                           \
            Bf[n] = *(const half8*)(Bb + n * 1024 + lane * 16);               \
        asm volatile("s_waitcnt lgkmcnt(0)" ::: "memory");                    \
        __builtin_amdgcn_sched_barrier(0); /* rule #18 fence */               \
        __builtin_amdgcn_s_barrier();      /* all waves done reading buf */   \
        if (DOISS) {                                                          \
            const int c2 = cc_ + 2;                                           \
            gload_lds16(EhB + (size_t)((c2 >> 3) * 8 + w) * 8192              \
                            + (c2 & 7) * 1024 + lane * 16,                    \
                        ldsB + (c2 & 1) * 8192 + w * 1024);                   \
        }                                                                     \
        __builtin_amdgcn_sched_barrier(0);                                    \
        __builtin_amdgcn_s_setprio(1);                                        \
        _Pragma("unroll")                                                     \
        for (int n = 0; n < 8; ++n)                                           \
            acc[n] = __builtin_amdgcn_mfma_f32_16x16x32_f16(Af, Bf[n], acc[n], 0, 0, 0); \
        __builtin_amdgcn_s_setprio(0);                                        \
    }

#define FOLD(GV)                                                              \
    {                                                                         \
        const int g_ = (GV);                                                  \
        float h2n[8];                                                         \
        _Pragma("unroll")                                                     \
        for (int n = 0; n < 8; ++n) h2n[n] = he2S[g_ * 128 + n * 16 + c15];   \
        const int colg0 = g_ * 128 + c15;                                     \
        _Pragma("unroll")                                                     \
        for (int reg = 0; reg < 4; ++reg) {                                   \
            float b1 = acc[0][reg] - h2n[0];                                  \
            int   i1 = colg0;                                                 \
            float b2 = -3.4e38f;                                              \
            _Pragma("unroll")                                                 \
            for (int n = 1; n < 8; ++n) {                                     \
                float s = acc[n][reg] - h2n[n];                               \
                int cI = colg0 + 16 * n;                                      \
                if (s > b1) { b2 = b1; b1 = s; i1 = cI; }                     \
                else        { b2 = fmaxf(b2, s); }                            \
            }                                                                 \
            _Pragma("unroll")                                                 \
            for (int msk = 1; msk <= 8; msk <<= 1) {                          \
                float ob1 = __shfl_xor(b1, msk, 64);                          \
                int   oi1 = __shfl_xor(i1, msk, 64);                          \
                float ob2 = __shfl_xor(b2, msk, 64);                          \
                if (ob1 > b1 || (ob1 == b1 && oi1 < i1)) {                    \
                    b2 = fmaxf(b1, ob2); b1 = ob1; i1 = oi1;                  \
                } else {                                                      \
                    b2 = fmaxf(b2, ob1);                                      \
                }                                                             \
            }                                                                 \
            if (c15 == 0) {                                                   \
                int rl = w * 16 + lhi * 4 + reg;                              \
                psB1[rl * 8 + g_] = b1;                                       \
                psI1[rl * 8 + g_] = i1;                                       \
                psB2[rl * 8 + g_] = b2;                                       \
            }                                                                 \
        }                                                                     \
    }

    #pragma unroll 1
    for (int g = 0; g < 7; ++g) {            // groups 0..6: uniform schedule
        #pragma unroll
        for (int n = 0; n < 8; ++n) acc[n] = (f32x4){0.f, 0.f, 0.f, 0.f};
        #pragma unroll
        for (int c = 0; c < 8; ++c)
            CHUNK(g * 8 + c, "s_waitcnt vmcnt(1)", true);
        FOLD(g);
    }
    {                                        // group 7 peeled (vmcnt tail)
        #pragma unroll
        for (int n = 0; n < 8; ++n) acc[n] = (f32x4){0.f, 0.f, 0.f, 0.f};
        #pragma unroll
        for (int c = 0; c < 6; ++c)
            CHUNK(56 + c, "s_waitcnt vmcnt(1)", true);
        CHUNK(62, "s_waitcnt vmcnt(1)", false);
        CHUNK(63, "s_waitcnt vmcnt(0)", false);
        FOLD(7);
    }
    __syncthreads();

    // ---- merge 8 group-partials per row (verified combine logic) ---------
    if (t < 128) {
        float b1 = psB1[t * 8]; int i1 = psI1[t * 8]; float b2 = psB2[t * 8];
        #pragma unroll
        for (int g = 1; g < 8; ++g) {
            float c1 = psB1[t * 8 + g]; int j1 = psI1[t * 8 + g];
            float c2 = psB2[t * 8 + g];
            if (c1 > b1 || (c1 == b1 && j1 < i1)) { b2 = fmaxf(b1, c2); b1 = c1; i1 = j1; }
            else                                  { b2 = fmaxf(b2, c1); }
        }
        idxS[t] = i1;
        outi[rowBase + t] = (float)i1;
        if (b1 - b2 < MARGIN) {
            int s = atomicAdd(&flagN, 1);
            flagL[s] = t;
        }
    }
    __syncthreads();

    // ---- gather: quantize[r][:] = embed[idx[r]][:] -----------------------
    #pragma unroll
    for (int q = 0; q < 16; ++q) {
        int f = t + 512 * q;
        int r = f >> 6, c4 = f & 63;
        int e = idxS[r];
        f32x4 v = *(const f32x4*)(embed + (size_t)e * DIMS + c4 * 4);
        *(f32x4*)(outq + (size_t)(rowBase + r) * DIMS + c4 * 4) = v;
    }
    __syncthreads();   // drain approx writes before rescue overwrites

    // ---- exact rescue: one wave per flagged row (verified rounds 11-13) --
    const int nf = flagN;
    const int q = c15, pgrp = lhi;
    for (int it = w; it < nf; it += 8) {
        int rl = flagL[it];
        int rrow = rowBase + rl;
        const f32x4* xr = (const f32x4*)(x + (size_t)rrow * DIMS + q * 16);
        f32x4 xa = xr[0], xb = xr[1], xc = xr[2], xd = xr[3];

        float pb1[8], pb2[8]; int pi1[8];
        #pragma unroll
        for (int g = 0; g < 8; ++g) {
            pb1[g] = psB1[rl * 8 + g];
            pi1[g] = psI1[rl * 8 + g];
            pb2[g] = psB2[rl * 8 + g];
        }
        float B1 = pb1[0];
        #pragma unroll
        for (int g = 1; g < 8; ++g) B1 = fmaxf(B1, pb1[g]);
        const float T = B1 - MARGIN;

        float wb = -3.4e38f; int wi = 0x7fffffff;
        #pragma unroll
        for (int g = 0; g < 8; ++g) {
            if (pb2[g] >= T) {
                #pragma unroll 2
                for (int i = 0; i < 32; ++i) {
                    int code = g * 128 + i * 4 + pgrp;
                    float s = dot16(xa, xb, xc, xd,
                                    embed + (size_t)code * DIMS, q) - he2[code];
                    if (s > wb || (s == wb && code < wi)) { wb = s; wi = code; }
                }
            } else if (pb1[g] >= T) {
                int code = pi1[g];
                float s = dot16(xa, xb, xc, xd,
                                embed + (size_t)code * DIMS, q) - he2[code];
                if (s > wb || (s == wb && code < wi)) { wb = s; wi = code; }
            }
        }
        #pragma unroll
        for (int msk = 16; msk <= 32; msk <<= 1) {
            float ob = __shfl_xor(wb, msk, 64);
            int   oi = __shfl_xor(wi, msk, 64);
            if (ob > wb || (ob == wb && oi < wi)) { wb = ob; wi = oi; }
        }
        f32x4 v = ((const f32x4*)(embed + (size_t)wi * DIMS))[lane];
        ((f32x4*)(outq + (size_t)rrow * DIMS))[lane] = v;
        if (lane == 0) outi[rrow] = (float)wi;
    }
#undef CHUNK
#undef FOLD
}

extern "C" void kernel_launch(void* const* d_in, const int* in_sizes, int n_in,
                              void* d_out, int out_size, void* d_ws, size_t ws_size,
                              hipStream_t stream) {
    const float* x     = (const float*)d_in[0];
    const float* embed = (const float*)d_in[1];
    char* ws = (char*)d_ws;
    float* he2 = (float*)ws;                 // 4 KB (+pad)
    short* Eh  = (short*)(ws + 8192);        // 512 KB fragment-ordered E
    float* out  = (float*)d_out;
    float* outi = out + (size_t)NROWS * DIMS;

    esplit<<<KCB / 4, 256, 0, stream>>>(embed, Eh, he2);
    vq_fused<<<NROWS / 128, 512, 0, stream>>>(x, embed, Eh, he2, out, outi);
}

// Round 15
// 91.967 us; speedup vs baseline: 1.0257x; 1.0257x over previous
//
#include <hip/hip_runtime.h>
#include <stdint.h>

#define NROWS 32768
#define DIMS  256
#define KCB   1024
#define BM 128
#define BN 128
#define GY (KCB/BN)   // 8 code-blocks
#define MARGIN 0.25f  // flag threshold AND rescue candidate window
#define CROWS 32      // rows per combine block

typedef _Float16 half8   __attribute__((ext_vector_type(8)));
typedef float    f32x4   __attribute__((ext_vector_type(4)));
typedef short    short4v __attribute__((ext_vector_type(4)));
typedef short    short8v __attribute__((ext_vector_type(8)));

__device__ __forceinline__ short f16h(float v) {
    _Float16 hh = (_Float16)v;
    return __builtin_bit_cast(short, hh);
}

// ---- X -> fragment-ordered f16 (h-plane only) ----------------------------
// group G (16 rows) blob = 8KB at byte G*8192; chunk c (32 k) = 1KB at
// +c*1024; lane l holds row G*16+(l&15), k=c*32+(l>>4)*8..+7 at byte l*16.
__global__ __launch_bounds__(256) void xsplit(const float* __restrict__ x,
                                              short* __restrict__ Xh) {
    int T = blockIdx.x * 256 + threadIdx.x;
    int l = T & 63, c = (T >> 6) & 7, G = T >> 9;
    int row = G * 16 + (l & 15);
    int kb  = c * 32 + (l >> 4) * 8;
    const f32x4* src = (const f32x4*)(x + (size_t)row * DIMS + kb);
    f32x4 a = src[0], b = src[1];
    short8v h;
    #pragma unroll
    for (int e = 0; e < 4; ++e) { h[e] = f16h(a[e]); h[4 + e] = f16h(b[e]); }
    *(short8v*)(Xh + (size_t)G * 4096 + c * 512 + l * 8) = h;
}

// ---- E -> fragment-ordered f16 (h-plane) + he2 ---------------------------
__global__ __launch_bounds__(256) void esplit(const float* __restrict__ embed,
                                              short* __restrict__ Eh,
                                              float* __restrict__ he2) {
    int r = blockIdx.x * 4 + (threadIdx.x >> 6);   // code row 0..1023
    int l = threadIdx.x & 63;
    f32x4 v = ((const f32x4*)(embed + (size_t)r * DIMS))[l];
    float s = v[0]*v[0] + v[1]*v[1] + v[2]*v[2] + v[3]*v[3];
    #pragma unroll
    for (int off = 32; off > 0; off >>= 1) s += __shfl_down(s, off, 64);
    if (l == 0) he2[r] = 0.5f * s;
    int G = r >> 4, cc = l >> 3;
    int fl = (r & 15) + 16 * ((l >> 1) & 3);
    size_t base = (size_t)G * 4096 + cc * 512 + fl * 8 + (l & 1) * 4;
    short4v h;
    #pragma unroll
    for (int e = 0; e < 4; ++e) h[e] = f16h(v[e]);
    *(short4v*)(Eh + base) = h;
}

// ---- approx GEMM + argmax(best,2nd): REGISTER-DIRECT, no LDS staging -----
// Fragment = 64 lanes x 16B contiguous in Xh/Eh => one global_load_dwordx4
// loads straight into the MFMA operand VGPRs. No LDS, no barriers, no
// lgkmcnt in the hot loop; fully unrolled 2-deep named double-buffer.
__global__ __launch_bounds__(256, 3) void vq_mfma(
    const short* __restrict__ Xh, const short* __restrict__ Eh,
    const float* __restrict__ he2, float4* __restrict__ part)
{
    __shared__ float sarr[BM * 2];
    __shared__ int   iarr[BM * 2];
    __shared__ float barr[BM * 2];

    const int t = threadIdx.x, lane = t & 63, w = t >> 6;
    const int wm = w >> 1, wn = w & 1;
    const int sid = blockIdx.x;
    const int xcd = sid & 7, j = sid >> 3;
    const int rb = xcd * 32 + (j >> 3), cb = j & 7;
    const int rowBase = rb * BM, colBase = cb * BN;

    const char* baseA = (const char*)Xh + (size_t)(rb * 8 + wm * 4) * 8192 + lane * 16;
    const char* baseB = (const char*)Eh + (size_t)(cb * 8 + wn * 4) * 8192 + lane * 16;

    f32x4 acc[4][4];
    #pragma unroll
    for (int m = 0; m < 4; ++m)
        #pragma unroll
        for (int n = 0; n < 4; ++n) acc[m][n] = (f32x4){0.f, 0.f, 0.f, 0.f};

#define LOADC(Ab, Bb, CC)                                                     \
    {                                                                         \
        _Pragma("unroll")                                                     \
        for (int m = 0; m < 4; ++m)                                           \
            Ab[m] = *(const half8*)(baseA + m * 8192 + (CC) * 1024);          \
        _Pragma("unroll")                                                     \
        for (int n = 0; n < 4; ++n)                                           \
            Bb[n] = *(const half8*)(baseB + n * 8192 + (CC) * 1024);          \
    }
#define DOMFMA(Ab, Bb)                                                        \
    {                                                                         \
        _Pragma("unroll")                                                     \
        for (int m = 0; m < 4; ++m)                                           \
            _Pragma("unroll")                                                 \
            for (int n = 0; n < 4; ++n)                                       \
                acc[m][n] = __builtin_amdgcn_mfma_f32_16x16x32_f16(           \
                    Ab[m], Bb[n], acc[m][n], 0, 0, 0);                        \
    }

    half8 A0[4], B0[4], A1[4], B1[4];
    LOADC(A0, B0, 0)
    LOADC(A1, B1, 1)
    DOMFMA(A0, B0)  LOADC(A0, B0, 2)
    DOMFMA(A1, B1)  LOADC(A1, B1, 3)
    DOMFMA(A0, B0)  LOADC(A0, B0, 4)
    DOMFMA(A1, B1)  LOADC(A1, B1, 5)
    DOMFMA(A0, B0)  LOADC(A0, B0, 6)
    DOMFMA(A1, B1)  LOADC(A1, B1, 7)
    DOMFMA(A0, B0)
    DOMFMA(A1, B1)
#undef LOADC
#undef DOMFMA

    // epilogue: per-row best + second-best (verified rounds 9-13)
    float h2[4];
    const int c15 = lane & 15;
    #pragma unroll
    for (int n = 0; n < 4; ++n) h2[n] = he2[colBase + 64 * wn + 16 * n + c15];
    const int colg0 = colBase + 64 * wn + c15;

    #pragma unroll
    for (int m = 0; m < 4; ++m) {
        #pragma unroll
        for (int reg = 0; reg < 4; ++reg) {
            float b1 = acc[m][0][reg] - h2[0];
            int   i1 = colg0;
            float b2 = -3.4e38f;
            #pragma unroll
            for (int n = 1; n < 4; ++n) {
                float s = acc[m][n][reg] - h2[n];
                if (s > b1) { b2 = b1; b1 = s; i1 = colg0 + 16 * n; }
                else        { b2 = fmaxf(b2, s); }
            }
            #pragma unroll
            for (int msk = 1; msk <= 8; msk <<= 1) {
                float ob1 = __shfl_xor(b1, msk, 64);
                int   oi1 = __shfl_xor(i1, msk, 64);
                float ob2 = __shfl_xor(b2, msk, 64);
                if (ob1 > b1 || (ob1 == b1 && oi1 < i1)) {
                    b2 = fmaxf(b1, ob2); b1 = ob1; i1 = oi1;
                } else {
                    b2 = fmaxf(b2, ob1);
                }
            }
            if (c15 == 0) {
                int row = 64 * wm + 16 * m + 4 * (lane >> 4) + reg;
                sarr[row * 2 + wn] = b1;
                iarr[row * 2 + wn] = i1;
                barr[row * 2 + wn] = b2;
            }
        }
    }
    __syncthreads();
    if (t < BM) {
        float s0 = sarr[t*2], s1 = sarr[t*2+1];
        int   i0 = iarr[t*2], i1 = iarr[t*2+1];
        float c0 = barr[t*2], c1 = barr[t*2+1];
        float b1, b2; int bi;
        if (s1 > s0) { b1 = s1; bi = i1; b2 = fmaxf(s0, c1); }   // i0<i1: ties keep i0
        else         { b1 = s0; bi = i0; b2 = fmaxf(s1, c0); }
        part[(size_t)(rowBase + t) * GY + cb] =
            make_float4(b1, __int_as_float(bi), b2, 0.f);
    }
}

// ---- 16-lane-group exact dot (verified rounds 11-13) ---------------------
__device__ __forceinline__ float dot16(f32x4 xa, f32x4 xb, f32x4 xc, f32x4 xd,
                                       const float* __restrict__ erow, int q) {
    const f32x4* er = (const f32x4*)(erow + q * 16);
    f32x4 ea = er[0], eb = er[1], ec = er[2], ed = er[3];
    float s = xa[0] * ea[0];
    s = fmaf(xa[1], ea[1], s); s = fmaf(xa[2], ea[2], s); s = fmaf(xa[3], ea[3], s);
    s = fmaf(xb[0], eb[0], s); s = fmaf(xb[1], eb[1], s);
    s = fmaf(xb[2], eb[2], s); s = fmaf(xb[3], eb[3], s);
    s = fmaf(xc[0], ec[0], s); s = fmaf(xc[1], ec[1], s);
    s = fmaf(xc[2], ec[2], s); s = fmaf(xc[3], ec[3], s);
    s = fmaf(xd[0], ed[0], s); s = fmaf(xd[1], ed[1], s);
    s = fmaf(xd[2], ed[2], s); s = fmaf(xd[3], ed[3], s);
    s += __shfl_xor(s, 1, 64);
    s += __shfl_xor(s, 2, 64);
    s += __shfl_xor(s, 4, 64);
    s += __shfl_xor(s, 8, 64);
    return s;
}

// ---- combine + gather + fused exact rescue: 32 rows/block, 1024 blocks ---
__global__ __launch_bounds__(256) void vq_combine(
    const float4* __restrict__ part, const float* __restrict__ embed,
    const float* __restrict__ x, const float* __restrict__ he2,
    float* __restrict__ outq, float* __restrict__ outi)
{
    __shared__ int idxS[CROWS];
    __shared__ int flagL[CROWS];
    __shared__ int flagN;
    const int t = threadIdx.x, l = t & 63, w = t >> 6;
    const int rowBase = blockIdx.x * CROWS;

    if (t == 0) flagN = 0;
    __syncthreads();

    if (t < CROWS) {
        const int row = rowBase + t;
        float4 p = part[(size_t)row * GY];
        float b1 = p.x; int i1 = __float_as_int(p.y); float b2 = p.z;
        #pragma unroll
        for (int g = 1; g < GY; ++g) {
            float4 q = part[(size_t)row * GY + g];
            float c1 = q.x; int j1 = __float_as_int(q.y); float c2 = q.z;
            if (c1 > b1 || (c1 == b1 && j1 < i1)) { b2 = fmaxf(b1, c2); b1 = c1; i1 = j1; }
            else                                  { b2 = fmaxf(b2, c1); }
        }
        idxS[t] = i1;
        outi[row] = (float)i1;
        if (b1 - b2 < MARGIN) {
            int s = atomicAdd(&flagN, 1);
            flagL[s] = t;
        }
    }
    __syncthreads();

    #pragma unroll
    for (int qq = 0; qq < (CROWS * 64) / 256; ++qq) {      // 8 iters
        int f = t + 256 * qq;
        int r = f >> 6, c4 = f & 63;
        int e = idxS[r];
        f32x4 v = *(const f32x4*)(embed + (size_t)e * DIMS + c4 * 4);
        *(f32x4*)(outq + (size_t)(rowBase + r) * DIMS + c4 * 4) = v;
    }
    __syncthreads();   // drain approx gather writes before rescue overwrites

    // rescue: one wave per flagged row (verified rounds 11-13)
    const int nf = flagN;
    const int q = l & 15, pgrp = l >> 4;
    for (int it = w; it < nf; it += 4) {
        int rrow = rowBase + flagL[it];
        const f32x4* xr = (const f32x4*)(x + (size_t)rrow * DIMS + q * 16);
        f32x4 xa = xr[0], xb = xr[1], xc = xr[2], xd = xr[3];

        float4 pc[GY];
        #pragma unroll
        for (int g = 0; g < GY; ++g) pc[g] = part[(size_t)rrow * GY + g];
        float B1 = pc[0].x;
        #pragma unroll
        for (int g = 1; g < GY; ++g) B1 = fmaxf(B1, pc[g].x);
        const float T = B1 - MARGIN;

        float wb = -3.4e38f; int wi = 0x7fffffff;
        #pragma unroll
        for (int g = 0; g < GY; ++g) {
            if (pc[g].z >= T) {
                #pragma unroll 2
                for (int i = 0; i < BN / 4; ++i) {
                    int code = g * BN + i * 4 + pgrp;
                    float s = dot16(xa, xb, xc, xd,
                                    embed + (size_t)code * DIMS, q) - he2[code];
                    if (s > wb || (s == wb && code < wi)) { wb = s; wi = code; }
                }
            } else if (pc[g].x >= T) {
                int code = __float_as_int(pc[g].y);
                float s = dot16(xa, xb, xc, xd,
                                embed + (size_t)code * DIMS, q) - he2[code];
                if (s > wb || (s == wb && code < wi)) { wb = s; wi = code; }
            }
        }
        #pragma unroll
        for (int msk = 16; msk <= 32; msk <<= 1) {
            float ob = __shfl_xor(wb, msk, 64);
            int   oi = __shfl_xor(wi, msk, 64);
            if (ob > wb || (ob == wb && oi < wi)) { wb = ob; wi = oi; }
        }
        f32x4 v = ((const f32x4*)(embed + (size_t)wi * DIMS))[l];
        ((f32x4*)(outq + (size_t)rrow * DIMS))[l] = v;
        if (l == 0) outi[rrow] = (float)wi;
    }
}

extern "C" void kernel_launch(void* const* d_in, const int* in_sizes, int n_in,
                              void* d_out, int out_size, void* d_ws, size_t ws_size,
                              hipStream_t stream) {
    const float* x     = (const float*)d_in[0];
    const float* embed = (const float*)d_in[1];
    char* ws = (char*)d_ws;
    float*  he2  = (float*)ws;                              // 4 KB (+pad)
    float4* part = (float4*)(ws + 8192);                    // 4 MB
    short*  Xh   = (short*)(ws + 8192 + 4194304);           // 16.8 MB
    short*  Eh   = (short*)(ws + 8192 + 4194304 + 16777216);// 512 KB
    float*  out  = (float*)d_out;
    float*  outi = out + (size_t)NROWS * DIMS;

    xsplit<<<4096, 256, 0, stream>>>(x, Xh);
    esplit<<<KCB / 4, 256, 0, stream>>>(embed, Eh, he2);
    vq_mfma<<<(NROWS / BM) * GY, 256, 0, stream>>>(Xh, Eh, he2, part);
    vq_combine<<<NROWS / CROWS, 256, 0, stream>>>(part, embed, x, he2, out, outi);
}

// Round 16
// 73.866 us; speedup vs baseline: 1.2771x; 1.2450x over previous
//
#include <hip/hip_runtime.h>
#include <stdint.h>

#define NROWS 32768
#define DIMS  256
#define KCB   1024
#define BM 128
#define BN 128
#define GY (KCB/BN)   // 8 code-blocks
#define MARGIN 0.25f  // flag threshold AND rescue candidate window
#define CROWS 32      // rows per combine block

typedef _Float16 half8   __attribute__((ext_vector_type(8)));
typedef float    f32x4   __attribute__((ext_vector_type(4)));
typedef short    short4v __attribute__((ext_vector_type(4)));
typedef short    short8v __attribute__((ext_vector_type(8)));

// async global->LDS, 16B per lane; LDS dest = wave-uniform base + lane*16
__device__ __forceinline__ void gload_lds16(const void* g, void* l) {
    __builtin_amdgcn_global_load_lds(
        (const __attribute__((address_space(1))) uint32_t*)g,
        (__attribute__((address_space(3))) uint32_t*)l, 16, 0, 0);
}

__device__ __forceinline__ short f16h(float v) {
    _Float16 hh = (_Float16)v;
    return __builtin_bit_cast(short, hh);
}

// ---- X -> fragment-ordered f16 (h-plane only) ----------------------------
__global__ __launch_bounds__(256) void xsplit(const float* __restrict__ x,
                                              short* __restrict__ Xh) {
    int T = blockIdx.x * 256 + threadIdx.x;
    int l = T & 63, c = (T >> 6) & 7, G = T >> 9;
    int row = G * 16 + (l & 15);
    int kb  = c * 32 + (l >> 4) * 8;
    const f32x4* src = (const f32x4*)(x + (size_t)row * DIMS + kb);
    f32x4 a = src[0], b = src[1];
    short8v h;
    #pragma unroll
    for (int e = 0; e < 4; ++e) { h[e] = f16h(a[e]); h[4 + e] = f16h(b[e]); }
    *(short8v*)(Xh + (size_t)G * 4096 + c * 512 + l * 8) = h;
}

// ---- E -> fragment-ordered f16 (h-plane) + he2 ---------------------------
__global__ __launch_bounds__(256) void esplit(const float* __restrict__ embed,
                                              short* __restrict__ Eh,
                                              float* __restrict__ he2) {
    int r = blockIdx.x * 4 + (threadIdx.x >> 6);   // code row 0..1023
    int l = threadIdx.x & 63;
    f32x4 v = ((const f32x4*)(embed + (size_t)r * DIMS))[l];
    float s = v[0]*v[0] + v[1]*v[1] + v[2]*v[2] + v[3]*v[3];
    #pragma unroll
    for (int off = 32; off > 0; off >>= 1) s += __shfl_down(s, off, 64);
    if (l == 0) he2[r] = 0.5f * s;
    int G = r >> 4, cc = l >> 3;
    int fl = (r & 15) + 16 * ((l >> 1) & 3);
    size_t base = (size_t)G * 4096 + cc * 512 + fl * 8 + (l & 1) * 4;
    short4v h;
    #pragma unroll
    for (int e = 0; e < 4; ++e) h[e] = f16h(v[e]);
    *(short4v*)(Eh + base) = h;
}

// ---- approx GEMM + argmax(best,2nd): barrier-free per-wave staging -------
// Hot loop identical to round 13 (48.3 us). Epilogue: LDS-assisted argmax
// reusing the dead staging buffer (1 shuffle mask + [128][17] triples).
__global__ __launch_bounds__(256, 4) void vq_mfma(
    const short* __restrict__ Xh, const short* __restrict__ Eh,
    const float* __restrict__ he2, float4* __restrict__ part)
{
    __shared__ char lds[32768];

    const int t = threadIdx.x, lane = t & 63, w = t >> 6;
    const int wm = w >> 1, wn = w & 1;
    const int lhi = lane >> 4, c15 = lane & 15;
    const int sid = blockIdx.x;
    const int xcd = sid & 7, j = sid >> 3;
    const int rb = xcd * 32 + (j >> 3), cb = j & 7;
    const int rowBase = rb * BM, colBase = cb * BN;

    const char* gA[4];
    const char* gB[4];
    #pragma unroll
    for (int m = 0; m < 4; ++m)
        gA[m] = (const char*)Xh + (size_t)(rb * 8 + wm * 4 + m) * 8192 + lane * 16;
    #pragma unroll
    for (int n = 0; n < 4; ++n)
        gB[n] = (const char*)Eh + (size_t)(cb * 8 + wn * 4 + n) * 8192 + lane * 16;
    char* lw = lds + w * 8192;

    f32x4 acc[4][4];
    #pragma unroll
    for (int m = 0; m < 4; ++m)
        #pragma unroll
        for (int n = 0; n < 4; ++n) acc[m][n] = (f32x4){0.f, 0.f, 0.f, 0.f};

    #pragma unroll
    for (int m = 0; m < 4; ++m) gload_lds16(gA[m], lw + m * 1024);
    #pragma unroll
    for (int n = 0; n < 4; ++n) gload_lds16(gB[n], lw + 4096 + n * 1024);

    #pragma unroll
    for (int c = 0; c < 8; ++c) {
        asm volatile("s_waitcnt vmcnt(0)" ::: "memory");   // my chunk arrived
        __builtin_amdgcn_sched_barrier(0);

        half8 A[4], B[4];
        #pragma unroll
        for (int m = 0; m < 4; ++m)
            A[m] = *(const half8*)(lw + m * 1024 + lane * 16);
        #pragma unroll
        for (int n = 0; n < 4; ++n)
            B[n] = *(const half8*)(lw + 4096 + n * 1024 + lane * 16);
        asm volatile("s_waitcnt lgkmcnt(0)" ::: "memory"); // regs loaded
        __builtin_amdgcn_sched_barrier(0);                 // rule #18 fence

        if (c < 7) {                                       // refill in place
            #pragma unroll
            for (int m = 0; m < 4; ++m)
                gload_lds16(gA[m] + (c + 1) * 1024, lw + m * 1024);
            #pragma unroll
            for (int n = 0; n < 4; ++n)
                gload_lds16(gB[n] + (c + 1) * 1024, lw + 4096 + n * 1024);
        }
        __builtin_amdgcn_sched_barrier(0);                 // loads before MFMA

        __builtin_amdgcn_s_setprio(1);
        #pragma unroll
        for (int m = 0; m < 4; ++m)
            #pragma unroll
            for (int n = 0; n < 4; ++n)
                acc[m][n] = __builtin_amdgcn_mfma_f32_16x16x32_f16(A[m], B[n], acc[m][n], 0, 0, 0);
        __builtin_amdgcn_s_setprio(0);
    }

    // ---- epilogue: LDS-assisted best/2nd argmax --------------------------
    __syncthreads();   // all waves done with staging LDS -> safe to alias
    float* S1 = (float*)lds;              // [128][17] f32  (8704 B)
    int*   I1 = (int*)(lds + 8704);       // [128][17] i32
    float* S2 = (float*)(lds + 17408);    // [128][17] f32  (total 26112 B)

    float h2[4];
    #pragma unroll
    for (int n = 0; n < 4; ++n) h2[n] = he2[colBase + 64 * wn + 16 * n + c15];
    const int colg0 = colBase + 64 * wn + c15;

    #pragma unroll
    for (int m = 0; m < 4; ++m) {
        #pragma unroll
        for (int reg = 0; reg < 4; ++reg) {
            float b1 = acc[m][0][reg] - h2[0];
            int   i1 = colg0;
            float b2 = -3.4e38f;
            #pragma unroll
            for (int n = 1; n < 4; ++n) {
                float s = acc[m][n][reg] - h2[n];
                if (s > b1) { b2 = b1; b1 = s; i1 = colg0 + 16 * n; }
                else        { b2 = fmaxf(b2, s); }
            }
            // single butterfly step: pair lanes (c15 even/odd)
            {
                float ob1 = __shfl_xor(b1, 1, 64);
                int   oi1 = __shfl_xor(i1, 1, 64);
                float ob2 = __shfl_xor(b2, 1, 64);
                if (ob1 > b1 || (ob1 == b1 && oi1 < i1)) {
                    b2 = fmaxf(b1, ob2); b1 = ob1; i1 = oi1;
                } else {
                    b2 = fmaxf(b2, ob1);
                }
            }
            if ((c15 & 1) == 0) {
                int row  = 64 * wm + 16 * m + 4 * lhi + reg;   // 0..127
                int slot = wn * 8 + (c15 >> 1);                // 0..15
                S1[row * 17 + slot] = b1;
                I1[row * 17 + slot] = i1;
                S2[row * 17 + slot] = b2;
            }
        }
    }
    __syncthreads();

    if (t < BM) {
        float b1 = S1[t * 17]; int i1 = I1[t * 17]; float b2 = S2[t * 17];
        #pragma unroll
        for (int s = 1; s < 16; ++s) {
            float c1 = S1[t * 17 + s]; int j1 = I1[t * 17 + s];
            float c2 = S2[t * 17 + s];
            if (c1 > b1 || (c1 == b1 && j1 < i1)) { b2 = fmaxf(b1, c2); b1 = c1; i1 = j1; }
            else                                  { b2 = fmaxf(b2, c1); }
        }
        part[(size_t)(rowBase + t) * GY + cb] =
            make_float4(b1, __int_as_float(i1), b2, 0.f);
    }
}

// ---- 16-lane-group exact dot (verified rounds 11-13) ---------------------
__device__ __forceinline__ float dot16(f32x4 xa, f32x4 xb, f32x4 xc, f32x4 xd,
                                       const float* __restrict__ erow, int q) {
    const f32x4* er = (const f32x4*)(erow + q * 16);
    f32x4 ea = er[0], eb = er[1], ec = er[2], ed = er[3];
    float s = xa[0] * ea[0];
    s = fmaf(xa[1], ea[1], s); s = fmaf(xa[2], ea[2], s); s = fmaf(xa[3], ea[3], s);
    s = fmaf(xb[0], eb[0], s); s = fmaf(xb[1], eb[1], s);
    s = fmaf(xb[2], eb[2], s); s = fmaf(xb[3], eb[3], s);
    s = fmaf(xc[0], ec[0], s); s = fmaf(xc[1], ec[1], s);
    s = fmaf(xc[2], ec[2], s); s = fmaf(xc[3], ec[3], s);
    s = fmaf(xd[0], ed[0], s); s = fmaf(xd[1], ed[1], s);
    s = fmaf(xd[2], ed[2], s); s = fmaf(xd[3], ed[3], s);
    s += __shfl_xor(s, 1, 64);
    s += __shfl_xor(s, 2, 64);
    s += __shfl_xor(s, 4, 64);
    s += __shfl_xor(s, 8, 64);
    return s;
}

// ---- combine + gather + fused exact rescue: 32 rows/block, 1024 blocks ---
__global__ __launch_bounds__(256) void vq_combine(
    const float4* __restrict__ part, const float* __restrict__ embed,
    const float* __restrict__ x, const float* __restrict__ he2,
    float* __restrict__ outq, float* __restrict__ outi)
{
    __shared__ int idxS[CROWS];
    __shared__ int flagL[CROWS];
    __shared__ int flagN;
    const int t = threadIdx.x, l = t & 63, w = t >> 6;
    const int rowBase = blockIdx.x * CROWS;

    if (t == 0) flagN = 0;
    __syncthreads();

    if (t < CROWS) {
        const int row = rowBase + t;
        float4 p = part[(size_t)row * GY];
        float b1 = p.x; int i1 = __float_as_int(p.y); float b2 = p.z;
        #pragma unroll
        for (int g = 1; g < GY; ++g) {
            float4 q = part[(size_t)row * GY + g];
            float c1 = q.x; int j1 = __float_as_int(q.y); float c2 = q.z;
            if (c1 > b1 || (c1 == b1 && j1 < i1)) { b2 = fmaxf(b1, c2); b1 = c1; i1 = j1; }
            else                                  { b2 = fmaxf(b2, c1); }
        }
        idxS[t] = i1;
        outi[row] = (float)i1;
        if (b1 - b2 < MARGIN) {
            int s = atomicAdd(&flagN, 1);
            flagL[s] = t;
        }
    }
    __syncthreads();

    #pragma unroll
    for (int qq = 0; qq < (CROWS * 64) / 256; ++qq) {      // 8 iters
        int f = t + 256 * qq;
        int r = f >> 6, c4 = f & 63;
        int e = idxS[r];
        f32x4 v = *(const f32x4*)(embed + (size_t)e * DIMS + c4 * 4);
        *(f32x4*)(outq + (size_t)(rowBase + r) * DIMS + c4 * 4) = v;
    }
    __syncthreads();   // drain approx gather writes before rescue overwrites

    // rescue: one wave per flagged row (verified rounds 11-13)
    const int nf = flagN;
    const int q = l & 15, pgrp = l >> 4;
    for (int it = w; it < nf; it += 4) {
        int rrow = rowBase + flagL[it];
        const f32x4* xr = (const f32x4*)(x + (size_t)rrow * DIMS + q * 16);
        f32x4 xa = xr[0], xb = xr[1], xc = xr[2], xd = xr[3];

        float4 pc[GY];
        #pragma unroll
        for (int g = 0; g < GY; ++g) pc[g] = part[(size_t)rrow * GY + g];
        float B1 = pc[0].x;
        #pragma unroll
        for (int g = 1; g < GY; ++g) B1 = fmaxf(B1, pc[g].x);
        const float T = B1 - MARGIN;

        float wb = -3.4e38f; int wi = 0x7fffffff;
        #pragma unroll
        for (int g = 0; g < GY; ++g) {
            if (pc[g].z >= T) {
                #pragma unroll 2
                for (int i = 0; i < BN / 4; ++i) {
                    int code = g * BN + i * 4 + pgrp;
                    float s = dot16(xa, xb, xc, xd,
                                    embed + (size_t)code * DIMS, q) - he2[code];
                    if (s > wb || (s == wb && code < wi)) { wb = s; wi = code; }
                }
            } else if (pc[g].x >= T) {
                int code = __float_as_int(pc[g].y);
                float s = dot16(xa, xb, xc, xd,
                                embed + (size_t)code * DIMS, q) - he2[code];
                if (s > wb || (s == wb && code < wi)) { wb = s; wi = code; }
            }
        }
        #pragma unroll
        for (int msk = 16; msk <= 32; msk <<= 1) {
            float ob = __shfl_xor(wb, msk, 64);
            int   oi = __shfl_xor(wi, msk, 64);
            if (ob > wb || (ob == wb && oi < wi)) { wb = ob; wi = oi; }
        }
        f32x4 v = ((const f32x4*)(embed + (size_t)wi * DIMS))[l];
        ((f32x4*)(outq + (size_t)rrow * DIMS))[l] = v;
        if (l == 0) outi[rrow] = (float)wi;
    }
}

extern "C" void kernel_launch(void* const* d_in, const int* in_sizes, int n_in,
                              void* d_out, int out_size, void* d_ws, size_t ws_size,
                              hipStream_t stream) {
    const float* x     = (const float*)d_in[0];
    const float* embed = (const float*)d_in[1];
    char* ws = (char*)d_ws;
    float*  he2  = (float*)ws;                              // 4 KB (+pad)
    float4* part = (float4*)(ws + 8192);                    // 4 MB
    short*  Xh   = (short*)(ws + 8192 + 4194304);           // 16.8 MB
    short*  Eh   = (short*)(ws + 8192 + 4194304 + 16777216);// 512 KB
    float*  out  = (float*)d_out;
    float*  outi = out + (size_t)NROWS * DIMS;

    xsplit<<<4096, 256, 0, stream>>>(x, Xh);
    esplit<<<KCB / 4, 256, 0, stream>>>(embed, Eh, he2);
    vq_mfma<<<(NROWS / BM) * GY, 256, 0, stream>>>(Xh, Eh, he2, part);
    vq_combine<<<NROWS / CROWS, 256, 0, stream>>>(part, embed, x, he2, out, outi);
}